// Round 1
// baseline (954.127 us; speedup 1.0000x reference)
//
#include <hip/hip_runtime.h>
#include <math.h>

#define M_ROWS 2048
#define N_COLS 2048
#define DIMS 512
#define IN_STRIDE 513
#define DP_BLOCKS 32
#define DP_COLS 64
#define BAND 16

constexpr float GAMMA = 0.001f;
constexpr float LOG2E = 1.44269504088896f;
constexpr float LN2   = 0.69314718055995f;

__device__ __forceinline__ float fexp2(float x) { return __builtin_amdgcn_exp2f(x); }
__device__ __forceinline__ float flog2(float x) { return __builtin_amdgcn_logf(x); }

// ---------------- argsort by timestamp (last column), stable ----------------
__global__ void argsort_kernel(const float* __restrict__ a, const float* __restrict__ b,
                               int* __restrict__ permA, int* __restrict__ permB) {
    const float* src = blockIdx.y ? b : a;
    int* perm = blockIdx.y ? permB : permA;
    __shared__ float keys[M_ROWS];
    for (int j = threadIdx.x; j < M_ROWS; j += blockDim.x)
        keys[j] = src[(size_t)j * IN_STRIDE + DIMS];
    __syncthreads();
    int i = blockIdx.x * blockDim.x + threadIdx.x;
    float ki = keys[i];
    int rank = 0;
    for (int j = 0; j < M_ROWS; ++j) {
        float kj = keys[j];
        rank += (kj < ki) || (kj == ki && j < i);
    }
    perm[rank] = i;
}

// ---------------- gather sorted rows + L2-normalize (drop time col) ----------------
__global__ __launch_bounds__(128) void norm_kernel(const float* __restrict__ a, const float* __restrict__ b,
                                                   const int* __restrict__ permA, const int* __restrict__ permB,
                                                   float* __restrict__ Ahat, float* __restrict__ Bhat) {
    const float* src = blockIdx.y ? b : a;
    const int* perm = blockIdx.y ? permB : permA;
    float* dst = blockIdx.y ? Bhat : Ahat;
    int r = blockIdx.x;
    int row = perm[r];
    const float* p = src + (size_t)row * IN_STRIDE;
    int tid = threadIdx.x;
    float v0 = p[tid], v1 = p[tid + 128], v2 = p[tid + 256], v3 = p[tid + 384];
    float ss = v0 * v0 + v1 * v1 + v2 * v2 + v3 * v3;
    #pragma unroll
    for (int off = 32; off > 0; off >>= 1) ss += __shfl_down(ss, off);
    __shared__ float red[2];
    if ((tid & 63) == 0) red[tid >> 6] = ss;
    __syncthreads();
    float inv = 1.0f / sqrtf(red[0] + red[1] + 1e-10f);
    float* q = dst + (size_t)r * DIMS;
    q[tid] = v0 * inv; q[tid + 128] = v1 * inv; q[tid + 256] = v2 * inv; q[tid + 384] = v3 * inv;
}

// ---------------- GEMM: Q[i][n] = exp(-1 - dot(Ahat[i], Bhat[n])) ----------------
__global__ __launch_bounds__(256) void gemm_kernel(const float* __restrict__ A, const float* __restrict__ B,
                                                   float* __restrict__ Q) {
    __shared__ float As[16][68];
    __shared__ float Bs[16][68];
    int tid = threadIdx.x;
    int tx = tid & 15, ty = tid >> 4;
    int row0 = blockIdx.y * 64;
    int col0 = blockIdx.x * 64;
    int lrow = tid >> 2;
    int lk = (tid & 3) * 4;
    const float* ap = A + (size_t)(row0 + lrow) * DIMS + lk;
    const float* bp = B + (size_t)(col0 + lrow) * DIMS + lk;
    float acc[4][4] = {};
    for (int k0 = 0; k0 < DIMS; k0 += 16) {
        float4 av = *(const float4*)ap; ap += 16;
        float4 bv = *(const float4*)bp; bp += 16;
        __syncthreads();
        As[lk + 0][lrow] = av.x; As[lk + 1][lrow] = av.y; As[lk + 2][lrow] = av.z; As[lk + 3][lrow] = av.w;
        Bs[lk + 0][lrow] = bv.x; Bs[lk + 1][lrow] = bv.y; Bs[lk + 2][lrow] = bv.z; Bs[lk + 3][lrow] = bv.w;
        __syncthreads();
        #pragma unroll
        for (int k = 0; k < 16; ++k) {
            float4 a4 = *(const float4*)&As[k][ty * 4];
            float4 b4 = *(const float4*)&Bs[k][tx * 4];
            float aa[4] = {a4.x, a4.y, a4.z, a4.w};
            float bb[4] = {b4.x, b4.y, b4.z, b4.w};
            #pragma unroll
            for (int u = 0; u < 4; ++u)
                #pragma unroll
                for (int v = 0; v < 4; ++v)
                    acc[u][v] += aa[u] * bb[v];
        }
    }
    #pragma unroll
    for (int u = 0; u < 4; ++u) {
        float4 o;
        o.x = __expf(-1.0f - acc[u][0]);
        o.y = __expf(-1.0f - acc[u][1]);
        o.z = __expf(-1.0f - acc[u][2]);
        o.w = __expf(-1.0f - acc[u][3]);
        *(float4*)&Q[(size_t)(row0 + ty * 4 + u) * N_COLS + col0 + tx * 4] = o;
    }
}

// ---------------- per-row softmax denom -> rs2 = log2e/(gamma*denom) ----------------
__global__ __launch_bounds__(256) void rowstat_kernel(const float* __restrict__ Q,
                                                      float* __restrict__ rowscale) {
    int i = blockIdx.x;
    const float* q = Q + (size_t)i * N_COLS;
    int tid = threadIdx.x;
    float4 x = *(const float4*)(q + tid * 4);
    float4 y = *(const float4*)(q + 1024 + tid * 4);
    float s = x.x + x.y + x.z + x.w + y.x + y.y + y.z + y.w;
    #pragma unroll
    for (int off = 32; off > 0; off >>= 1) s += __shfl_down(s, off);
    __shared__ float red[4];
    if ((tid & 63) == 0) red[tid >> 6] = s;
    __syncthreads();
    if (tid == 0) {
        float denom = 2049.0f + red[0] + red[1] + red[2] + red[3];
        rowscale[i] = (LOG2E / GAMMA) / denom;
    }
}

// ---------------- LG2T[col][row] = log2(We_row + Wo_row[col]), tiled transpose ----------
__global__ __launch_bounds__(256) void lgt_kernel(const float* __restrict__ Q,
                                                  const float* __restrict__ rowscale,
                                                  float* __restrict__ LG2T) {
    __shared__ float tile[64][65];
    const int row0 = blockIdx.y * 64;
    const int col0 = blockIdx.x * 64;
    const int t = threadIdx.x;
    const int c4 = (t & 15) * 4;
    const int r  = t >> 4;           // 0..15
    #pragma unroll
    for (int rr = 0; rr < 64; rr += 16) {
        int row = row0 + rr + r;
        float rs = rowscale[row];
        float4 v = *(const float4*)(Q + (size_t)row * N_COLS + col0 + c4);
        float e = fexp2(-rs);
        tile[c4 + 0][rr + r] = flog2(e + fexp2(-rs * v.x));
        tile[c4 + 1][rr + r] = flog2(e + fexp2(-rs * v.y));
        tile[c4 + 2][rr + r] = flog2(e + fexp2(-rs * v.z));
        tile[c4 + 3][rr + r] = flog2(e + fexp2(-rs * v.w));
    }
    __syncthreads();
    #pragma unroll
    for (int cc = 0; cc < 64; cc += 16) {
        int col = cc + r;
        float4 o;
        o.x = tile[col][c4 + 0];
        o.y = tile[col][c4 + 1];
        o.z = tile[col][c4 + 2];
        o.w = tile[col][c4 + 3];
        *(float4*)(LG2T + (size_t)(col0 + col) * M_ROWS + row0 + c4) = o;
    }
}

// ---------------- (m,s) pair arithmetic: value = m + log2(s) ----------------
struct Pair { float m, s; };
constexpr float ID_M = -1e30f;

__device__ __forceinline__ Pair pcomb(Pair a, Pair b) {
    float e = fexp2(-fabsf(a.m - b.m));
    bool c = a.m >= b.m;
    Pair r;
    r.m = c ? a.m : b.m;
    r.s = c ? fmaf(b.s, e, a.s) : fmaf(a.s, e, b.s);
    return r;
}
// 1-chain-op renorm via v_frexp_mant / v_frexp_exp
__device__ __forceinline__ void renorm(float& m, float& s) {
    int ex = __builtin_amdgcn_frexp_expf(s);
    s = __builtin_amdgcn_frexp_mantf(s);
    m += (float)ex;
}
template<int CTRL, int ROWM>
__device__ __forceinline__ float fdpp(float oldv, float src) {
    return __int_as_float(__builtin_amdgcn_update_dpp(
        __float_as_int(oldv), __float_as_int(src), CTRL, ROWM, 0xF, false));
}
// wave64 inclusive AFFINE scan: S[n] = S[n-1]*a[n] + z[n]; mul+fma only.
__device__ __forceinline__ void affine_scan(float& A, float& S) {
    { float Ap = fdpp<0x111,0xF>(1.0f, A), Sp = fdpp<0x111,0xF>(0.0f, S); S = fmaf(Sp, A, S); A = A * Ap; }
    { float Ap = fdpp<0x112,0xF>(1.0f, A), Sp = fdpp<0x112,0xF>(0.0f, S); S = fmaf(Sp, A, S); A = A * Ap; }
    { float Ap = fdpp<0x114,0xF>(1.0f, A), Sp = fdpp<0x114,0xF>(0.0f, S); S = fmaf(Sp, A, S); A = A * Ap; }
    { float Ap = fdpp<0x118,0xF>(1.0f, A), Sp = fdpp<0x118,0xF>(0.0f, S); S = fmaf(Sp, A, S); A = A * Ap; }
    { float Ap = fdpp<0x142,0xA>(1.0f, A), Sp = fdpp<0x142,0xA>(0.0f, S); S = fmaf(Sp, A, S); A = A * Ap; }
    { float Ap = fdpp<0x143,0xC>(1.0f, A), Sp = fdpp<0x143,0xC>(0.0f, S); S = fmaf(Sp, A, S); A = A * Ap; }
}
// lane (n-1) value, crossing 16-lane DPP row boundaries; lane 0 gets idv
__device__ __forceinline__ float lane_prev(float x, int lane, float idv) {
    float am = fdpp<0x111,0xF>(idv, x);
    float bm = fdpp<0x142,0xA>(idv, x);
    float cm = fdpp<0x143,0x4>(idv, x);
    bool s15 = (lane == 16) || (lane == 48);
    bool s31 = (lane == 32);
    return s15 ? bm : (s31 ? cm : am);
}

// ---------------- row body ----------------
// Chain-optimized vs previous round:
//  * Tp = lane_prev(S) eliminated: Tp*2^(Gp-m3) == (S-sP)*2^(G-m3) exactly
//    (telescoping), so the post-scan tail is S -> sub -> fma (2 ops).
//  * renorm deferred to every 4th row (RN=1). Growth <= ~200x/row keeps
//    sP <= ~1.6e9 between renorms; m-field drift <= ~31 so all exp2 args and
//    pcomb deltas stay in range. On RN=0 rows mP = m3 directly, decoupling the
//    next row's G/Gp/A=exp2 from this row's s-chain (they overlap the scan).
//  * eb (cin + diagonal terms) is computed before the scan, off the chain.
#define DP_ROW(U, LGV, RSV, RN)                                                  \
    {                                                                            \
        const int row = base + (U);                                              \
        float lwe = -(RSV);                                                      \
        float G = mP + (LGV);                                                    \
        float Gp = lane_prev(G, lane, ID_M);       /* lane0 -> -1e30 */          \
        float A = fexp2(Gp - G);                   /* lane0 -> 0 */              \
        float dm = mP + lwe;                                                     \
        Pair cin{ID_M, 0.f};                                                     \
        if (s > 0) {                                                             \
            cin.m = __int_as_float(__builtin_amdgcn_readlane(pkLo, (U)));        \
            cin.s = __int_as_float(__builtin_amdgcn_readlane(pkHi, (U)));        \
        }                                                                        \
        float m3 = fmaxf(fmaxf(cin.m, G), dm);                                   \
        float e2 = fexp2(G - m3);                                                \
        float eb = fmaf(sP, fexp2(dm - m3), cin.s * fexp2(cin.m - m3));          \
        float S = sP;                                                            \
        affine_scan(A, S);                                                       \
        float s3 = fmaf(S - sP, e2, eb);                                         \
        float mN = m3;                                                           \
        if (RN) {                                                                \
            mN = m3 + (float)__builtin_amdgcn_frexp_expf(s3);                    \
            s3 = __builtin_amdgcn_frexp_mantf(s3);                               \
        }                                                                        \
        if (s < DP_BLOCKS - 1) {                                                 \
            if (lane == 63) {                                                    \
                Pair tot = pcomb(cin, Pair{G, S});                               \
                unsigned long long po =                                          \
                    ((unsigned long long)__float_as_uint(tot.s) << 32)           \
                    | (unsigned long long)__float_as_uint(tot.m);                \
                __hip_atomic_store(pub + row, po, __ATOMIC_RELAXED,              \
                                   __HIP_MEMORY_SCOPE_AGENT);                    \
            }                                                                    \
        } else {                                                                 \
            Pair tot = pcomb(cin, Pair{G, S});                                   \
            Pair hh = pcomb(tot, Pair{mH + lwe, sH});                            \
            mH = hh.m; sH = hh.s;                                                \
            renorm(mH, sH);                                                      \
        }                                                                        \
        mP = mN; sP = s3;                                                        \
    }

// Wait only for the 4-row sub-group we are about to consume: cuts the
// inter-stripe pipeline skew from 16 rows to 4 rows per stripe.
#define WAIT_GROUP(g)                                                            \
    do {                                                                         \
        if (s > 0) {                                                             \
            for (;;) {                                                           \
                unsigned long long miss =                                        \
                    __ballot((lane >> 2) == (g) && pk == 0ull);                  \
                if (miss == 0ull) break;                                         \
                if ((lane >> 2) == (g) && pk == 0ull)                            \
                    pk = __hip_atomic_load(sub + base + lane, __ATOMIC_RELAXED,  \
                                           __HIP_MEMORY_SCOPE_AGENT);           \
            }                                                                    \
            pkLo = (int)(unsigned)(pk & 0xFFFFFFFFull);                          \
            pkHi = (int)(unsigned)(pk >> 32);                                    \
        }                                                                        \
    } while (0);

__global__ __launch_bounds__(64) void dp_kernel(const float* __restrict__ LG2T,
                                                const float* __restrict__ Rs,
                                                unsigned long long* __restrict__ carry,
                                                float* __restrict__ out) {
    const int s = ((blockIdx.x & 7) << 2) | (blockIdx.x >> 3);  // XCD-aware stripe id
    const int lane = threadIdx.x;
    const float* lcol = LG2T + (size_t)(s * DP_COLS + lane) * M_ROWS;
    unsigned long long* pub = carry + (size_t)s * M_ROWS;
    const unsigned long long* sub = carry + (size_t)(s - 1) * M_ROWS;

    float mP = 0.f, sP = 1.f;      // virtual row -1: P = log2(1)
    float mH = 0.f, sH = 1.f;      // stripe 31, lane 63 only

    float4 lq0 = *(const float4*)(lcol + 0);
    float4 lq1 = *(const float4*)(lcol + 4);
    float4 lq2 = *(const float4*)(lcol + 8);
    float4 lq3 = *(const float4*)(lcol + 12);
    float4 rv0 = *(const float4*)(Rs + 0);
    float4 rv1 = *(const float4*)(Rs + 4);
    float4 rv2 = *(const float4*)(Rs + 8);
    float4 rv3 = *(const float4*)(Rs + 12);

    // speculative carry prefetch for band 0
    unsigned long long pk = 1ull;
    if (s > 0 && lane < BAND)
        pk = __hip_atomic_load(sub + lane, __ATOMIC_RELAXED, __HIP_MEMORY_SCOPE_AGENT);

    for (int base = 0; base < M_ROWS; base += BAND) {
        // prefetch next band's weights (independent; completes during the 16 rows)
        float4 nl0{}, nl1{}, nl2{}, nl3{}, nv0{}, nv1{}, nv2{}, nv3{};
        if (base + BAND < M_ROWS) {
            nl0 = *(const float4*)(lcol + base + BAND);
            nl1 = *(const float4*)(lcol + base + BAND + 4);
            nl2 = *(const float4*)(lcol + base + BAND + 8);
            nl3 = *(const float4*)(lcol + base + BAND + 12);
            nv0 = *(const float4*)(Rs + base + BAND);
            nv1 = *(const float4*)(Rs + base + BAND + 4);
            nv2 = *(const float4*)(Rs + base + BAND + 8);
            nv3 = *(const float4*)(Rs + base + BAND + 12);
        }
        int pkLo = 0, pkHi = 0;

        WAIT_GROUP(0)
        DP_ROW(0,  lq0.x, rv0.x, 0)
        DP_ROW(1,  lq0.y, rv0.y, 0)
        DP_ROW(2,  lq0.z, rv0.z, 0)
        DP_ROW(3,  lq0.w, rv0.w, 1)
        WAIT_GROUP(1)
        DP_ROW(4,  lq1.x, rv1.x, 0)
        DP_ROW(5,  lq1.y, rv1.y, 0)
        DP_ROW(6,  lq1.z, rv1.z, 0)
        DP_ROW(7,  lq1.w, rv1.w, 1)
        WAIT_GROUP(2)
        DP_ROW(8,  lq2.x, rv2.x, 0)
        DP_ROW(9,  lq2.y, rv2.y, 0)
        DP_ROW(10, lq2.z, rv2.z, 0)
        DP_ROW(11, lq2.w, rv2.w, 1)
        WAIT_GROUP(3)
        // speculative carry load for the NEXT band (in flight during rows 12-15
        // and the next band's weight prefetch)
        {
            unsigned long long nk = 1ull;
            if (s > 0 && lane < BAND && base + BAND < M_ROWS)
                nk = __hip_atomic_load(sub + base + BAND + lane,
                                       __ATOMIC_RELAXED, __HIP_MEMORY_SCOPE_AGENT);
            DP_ROW(12, lq3.x, rv3.x, 0)
            DP_ROW(13, lq3.y, rv3.y, 0)
            DP_ROW(14, lq3.z, rv3.z, 0)
            DP_ROW(15, lq3.w, rv3.w, 1)
            pk = nk;
        }

        lq0 = nl0; lq1 = nl1; lq2 = nl2; lq3 = nl3;
        rv0 = nv0; rv1 = nv1; rv2 = nv2; rv3 = nv3;
    }
    if (s == DP_BLOCKS - 1 && lane == 63)
        out[0] = -GAMMA * LN2 * (mH + flog2(sH));
}

extern "C" void kernel_launch(void* const* d_in, const int* in_sizes, int n_in,
                              void* d_out, int out_size, void* d_ws, size_t ws_size,
                              hipStream_t stream) {
    (void)in_sizes; (void)n_in; (void)out_size; (void)ws_size;
    const float* a = (const float*)d_in[0];
    const float* b = (const float*)d_in[1];
    float* out = (float*)d_out;
    char* ws = (char*)d_ws;
    float* Q        = (float*)(ws);                                    // 16 MB
    float* LG2T     = (float*)(ws + (size_t)16 * 1024 * 1024);         // 16 MB
    float* Ahat     = (float*)(ws + (size_t)32 * 1024 * 1024);         // 4 MB
    float* Bhat     = (float*)(ws + (size_t)36 * 1024 * 1024);         // 4 MB
    float* rowscale = (float*)(ws + (size_t)40 * 1024 * 1024);         // 8 KB
    int* permA      = (int*)(ws + (size_t)40 * 1024 * 1024 + 8192);    // 8 KB
    int* permB      = (int*)(ws + (size_t)40 * 1024 * 1024 + 16384);   // 8 KB
    unsigned long long* carry = (unsigned long long*)(ws + (size_t)41 * 1024 * 1024); // 512 KB

    hipMemsetAsync(carry, 0, (size_t)DP_BLOCKS * M_ROWS * sizeof(unsigned long long), stream);
    argsort_kernel<<<dim3(8, 2), 256, 0, stream>>>(a, b, permA, permB);
    norm_kernel<<<dim3(2048, 2), 128, 0, stream>>>(a, b, permA, permB, Ahat, Bhat);
    gemm_kernel<<<dim3(32, 32), 256, 0, stream>>>(Ahat, Bhat, Q);
    rowstat_kernel<<<2048, 256, 0, stream>>>(Q, rowscale);
    lgt_kernel<<<dim3(32, 32), 256, 0, stream>>>(Q, rowscale, LG2T);
    dp_kernel<<<DP_BLOCKS, DP_COLS, 0, stream>>>(LG2T, rowscale, carry, out);
}

// Round 2
// 899.081 us; speedup vs baseline: 1.0612x; 1.0612x over previous
//
#include <hip/hip_runtime.h>
#include <math.h>

#define M_ROWS 2048
#define N_COLS 2048
#define DIMS 512
#define IN_STRIDE 513
#define DP_BLOCKS 32
#define DP_COLS 64
#define BAND 16

constexpr float GAMMA = 0.001f;
constexpr float LOG2E = 1.44269504088896f;
constexpr float LN2   = 0.69314718055995f;

__device__ __forceinline__ float fexp2(float x) { return __builtin_amdgcn_exp2f(x); }
__device__ __forceinline__ float flog2(float x) { return __builtin_amdgcn_logf(x); }

// ---------------- argsort by timestamp (last column), stable ----------------
__global__ void argsort_kernel(const float* __restrict__ a, const float* __restrict__ b,
                               int* __restrict__ permA, int* __restrict__ permB) {
    const float* src = blockIdx.y ? b : a;
    int* perm = blockIdx.y ? permB : permA;
    __shared__ float keys[M_ROWS];
    for (int j = threadIdx.x; j < M_ROWS; j += blockDim.x)
        keys[j] = src[(size_t)j * IN_STRIDE + DIMS];
    __syncthreads();
    int i = blockIdx.x * blockDim.x + threadIdx.x;
    float ki = keys[i];
    int rank = 0;
    for (int j = 0; j < M_ROWS; ++j) {
        float kj = keys[j];
        rank += (kj < ki) || (kj == ki && j < i);
    }
    perm[rank] = i;
}

// ---------------- gather sorted rows + L2-normalize (drop time col) ----------------
__global__ __launch_bounds__(128) void norm_kernel(const float* __restrict__ a, const float* __restrict__ b,
                                                   const int* __restrict__ permA, const int* __restrict__ permB,
                                                   float* __restrict__ Ahat, float* __restrict__ Bhat) {
    const float* src = blockIdx.y ? b : a;
    const int* perm = blockIdx.y ? permB : permA;
    float* dst = blockIdx.y ? Bhat : Ahat;
    int r = blockIdx.x;
    int row = perm[r];
    const float* p = src + (size_t)row * IN_STRIDE;
    int tid = threadIdx.x;
    float v0 = p[tid], v1 = p[tid + 128], v2 = p[tid + 256], v3 = p[tid + 384];
    float ss = v0 * v0 + v1 * v1 + v2 * v2 + v3 * v3;
    #pragma unroll
    for (int off = 32; off > 0; off >>= 1) ss += __shfl_down(ss, off);
    __shared__ float red[2];
    if ((tid & 63) == 0) red[tid >> 6] = ss;
    __syncthreads();
    float inv = 1.0f / sqrtf(red[0] + red[1] + 1e-10f);
    float* q = dst + (size_t)r * DIMS;
    q[tid] = v0 * inv; q[tid + 128] = v1 * inv; q[tid + 256] = v2 * inv; q[tid + 384] = v3 * inv;
}

// ---------------- GEMM: Q[i][n] = exp(-1 - dot(Ahat[i], Bhat[n])) ----------------
__global__ __launch_bounds__(256) void gemm_kernel(const float* __restrict__ A, const float* __restrict__ B,
                                                   float* __restrict__ Q) {
    __shared__ float As[16][68];
    __shared__ float Bs[16][68];
    int tid = threadIdx.x;
    int tx = tid & 15, ty = tid >> 4;
    int row0 = blockIdx.y * 64;
    int col0 = blockIdx.x * 64;
    int lrow = tid >> 2;
    int lk = (tid & 3) * 4;
    const float* ap = A + (size_t)(row0 + lrow) * DIMS + lk;
    const float* bp = B + (size_t)(col0 + lrow) * DIMS + lk;
    float acc[4][4] = {};
    for (int k0 = 0; k0 < DIMS; k0 += 16) {
        float4 av = *(const float4*)ap; ap += 16;
        float4 bv = *(const float4*)bp; bp += 16;
        __syncthreads();
        As[lk + 0][lrow] = av.x; As[lk + 1][lrow] = av.y; As[lk + 2][lrow] = av.z; As[lk + 3][lrow] = av.w;
        Bs[lk + 0][lrow] = bv.x; Bs[lk + 1][lrow] = bv.y; Bs[lk + 2][lrow] = bv.z; Bs[lk + 3][lrow] = bv.w;
        __syncthreads();
        #pragma unroll
        for (int k = 0; k < 16; ++k) {
            float4 a4 = *(const float4*)&As[k][ty * 4];
            float4 b4 = *(const float4*)&Bs[k][tx * 4];
            float aa[4] = {a4.x, a4.y, a4.z, a4.w};
            float bb[4] = {b4.x, b4.y, b4.z, b4.w};
            #pragma unroll
            for (int u = 0; u < 4; ++u)
                #pragma unroll
                for (int v = 0; v < 4; ++v)
                    acc[u][v] += aa[u] * bb[v];
        }
    }
    #pragma unroll
    for (int u = 0; u < 4; ++u) {
        float4 o;
        o.x = __expf(-1.0f - acc[u][0]);
        o.y = __expf(-1.0f - acc[u][1]);
        o.z = __expf(-1.0f - acc[u][2]);
        o.w = __expf(-1.0f - acc[u][3]);
        *(float4*)&Q[(size_t)(row0 + ty * 4 + u) * N_COLS + col0 + tx * 4] = o;
    }
}

// ---------------- per-row softmax denom -> rs2 = log2e/(gamma*denom) ----------------
__global__ __launch_bounds__(256) void rowstat_kernel(const float* __restrict__ Q,
                                                      float* __restrict__ rowscale) {
    int i = blockIdx.x;
    const float* q = Q + (size_t)i * N_COLS;
    int tid = threadIdx.x;
    float4 x = *(const float4*)(q + tid * 4);
    float4 y = *(const float4*)(q + 1024 + tid * 4);
    float s = x.x + x.y + x.z + x.w + y.x + y.y + y.z + y.w;
    #pragma unroll
    for (int off = 32; off > 0; off >>= 1) s += __shfl_down(s, off);
    __shared__ float red[4];
    if ((tid & 63) == 0) red[tid >> 6] = s;
    __syncthreads();
    if (tid == 0) {
        float denom = 2049.0f + red[0] + red[1] + red[2] + red[3];
        rowscale[i] = (LOG2E / GAMMA) / denom;
    }
}

// ---------------- LG2T[col][row] = log2(We_row + Wo_row[col]), tiled transpose ----------
__global__ __launch_bounds__(256) void lgt_kernel(const float* __restrict__ Q,
                                                  const float* __restrict__ rowscale,
                                                  float* __restrict__ LG2T) {
    __shared__ float tile[64][65];
    const int row0 = blockIdx.y * 64;
    const int col0 = blockIdx.x * 64;
    const int t = threadIdx.x;
    const int c4 = (t & 15) * 4;
    const int r  = t >> 4;           // 0..15
    #pragma unroll
    for (int rr = 0; rr < 64; rr += 16) {
        int row = row0 + rr + r;
        float rs = rowscale[row];
        float4 v = *(const float4*)(Q + (size_t)row * N_COLS + col0 + c4);
        float e = fexp2(-rs);
        tile[c4 + 0][rr + r] = flog2(e + fexp2(-rs * v.x));
        tile[c4 + 1][rr + r] = flog2(e + fexp2(-rs * v.y));
        tile[c4 + 2][rr + r] = flog2(e + fexp2(-rs * v.z));
        tile[c4 + 3][rr + r] = flog2(e + fexp2(-rs * v.w));
    }
    __syncthreads();
    #pragma unroll
    for (int cc = 0; cc < 64; cc += 16) {
        int col = cc + r;
        float4 o;
        o.x = tile[col][c4 + 0];
        o.y = tile[col][c4 + 1];
        o.z = tile[col][c4 + 2];
        o.w = tile[col][c4 + 3];
        *(float4*)(LG2T + (size_t)(col0 + col) * M_ROWS + row0 + c4) = o;
    }
}

// ---------------- (m,s) pair arithmetic: value = m + log2(s) ----------------
struct Pair { float m, s; };
constexpr float ID_M = -1e30f;

__device__ __forceinline__ Pair pcomb(Pair a, Pair b) {
    float e = fexp2(-fabsf(a.m - b.m));
    bool c = a.m >= b.m;
    Pair r;
    r.m = c ? a.m : b.m;
    r.s = c ? fmaf(b.s, e, a.s) : fmaf(a.s, e, b.s);
    return r;
}
// 1-chain-op renorm via v_frexp_mant / v_frexp_exp
__device__ __forceinline__ void renorm(float& m, float& s) {
    int ex = __builtin_amdgcn_frexp_expf(s);
    s = __builtin_amdgcn_frexp_mantf(s);
    m += (float)ex;
}
template<int CTRL, int ROWM>
__device__ __forceinline__ float fdpp(float oldv, float src) {
    return __int_as_float(__builtin_amdgcn_update_dpp(
        __float_as_int(oldv), __float_as_int(src), CTRL, ROWM, 0xF, false));
}
// lane (n-1) value, crossing 16-lane DPP row boundaries; lane 0 gets idv
__device__ __forceinline__ float lane_prev(float x, int lane, float idv) {
    float am = fdpp<0x111,0xF>(idv, x);
    float bm = fdpp<0x142,0xA>(idv, x);
    float cm = fdpp<0x143,0x4>(idv, x);
    bool s15 = (lane == 16) || (lane == 48);
    bool s31 = (lane == 32);
    return s15 ? bm : (s31 ? cm : am);
}

// One stage of the fused 2-row lower-triangular matrix affine scan.
// State per lane: T = [[a,0],[c,d]], b = (bu,bv).  Combine own ∘ prev:
//   T_new = T*T', b_new = T*b' + b.  Identities: a'=d'=1, c'=bu'=bv'=0.
#define MSTAGE(CTRL, ROWM)                                                       \
    {                                                                            \
        float ap  = fdpp<CTRL, ROWM>(1.0f, a);                                   \
        float cp  = fdpp<CTRL, ROWM>(0.0f, c);                                   \
        float dpv = fdpp<CTRL, ROWM>(1.0f, d);                                   \
        float bup = fdpp<CTRL, ROWM>(0.0f, bu);                                  \
        float bvp = fdpp<CTRL, ROWM>(0.0f, bv);                                  \
        bv = fmaf(c, bup, fmaf(d, bvp, bv));                                     \
        bu = fmaf(a, bup, bu);                                                   \
        float tt = d * cp;                                                       \
        c = fmaf(c, ap, tt);                                                     \
        a = a * ap;                                                              \
        d = d * dpv;                                                             \
    }

// ---------------- fused 2-row body ----------------
// Row i:   u[n] = A0[n]*u[n-1] + sP[n]            (u init = sP, A0[wave-lane0]=0)
//          s3_0[n] = e20[n]*u[n] + beta0[n]
// Row i+1: v[n] = A1[n]*v[n-1] + s3_0[n]
//                = A1*v[n-1] + e20*u[n] + beta0   -> lower-tri 2x2 matrix scan
//          with T=[[A0,0],[e20*A0,A1]], b=(sP, eb0)   (since e20*sP+beta0 = eb0)
//          s3_1[n] = (v - s3_0)*e21 + ec1 + s3_0*ed1
//                  = v*e21 + u*k1 + k0,  k1=e20*(ed1-e21), k0=beta0*(ed1-e21)+ec1
// m-chain (maxes) never passes through the scan, so both rows' coefficients are
// computed up front; one 6-stage DPP scan advances two rows.  renorm every 2nd
// pair (= every 4 rows), same cadence as the previous passing version.
#define DP_PAIR(U0, LGV0, RSV0, LGV1, RSV1, RN)                                  \
    {                                                                            \
        const int row = base + (U0);                                             \
        float lwe0 = -(RSV0), lwe1 = -(RSV1);                                    \
        Pair cin0{ID_M, 0.f}, cin1{ID_M, 0.f};                                   \
        if (s > 0) {                                                             \
            cin0.m = __int_as_float(__builtin_amdgcn_readlane(pkLo, (U0)));      \
            cin0.s = __int_as_float(__builtin_amdgcn_readlane(pkHi, (U0)));      \
            cin1.m = __int_as_float(__builtin_amdgcn_readlane(pkLo, (U0) + 1));  \
            cin1.s = __int_as_float(__builtin_amdgcn_readlane(pkHi, (U0) + 1));  \
        }                                                                        \
        float G0 = mP + (LGV0);                                                  \
        float Gp0 = lane_prev(G0, lane, ID_M);                                   \
        float A0 = fexp2(Gp0 - G0);                                              \
        float dm0 = mP + lwe0;                                                   \
        float m30 = fmaxf(fmaxf(cin0.m, G0), dm0);                               \
        float e20 = fexp2(G0 - m30);                                             \
        float eb0 = fmaf(sP, fexp2(dm0 - m30), cin0.s * fexp2(cin0.m - m30));    \
        float G1 = m30 + (LGV1);                                                 \
        float Gp1 = lane_prev(G1, lane, ID_M);                                   \
        float A1 = fexp2(Gp1 - G1);                                              \
        float dm1 = m30 + lwe1;                                                  \
        float m31 = fmaxf(fmaxf(cin1.m, G1), dm1);                               \
        float e21 = fexp2(G1 - m31);                                             \
        float ed1 = fexp2(dm1 - m31);                                            \
        float ec1 = cin1.s * fexp2(cin1.m - m31);                                \
        float beta0 = fmaf(-sP, e20, eb0);                                       \
        float dlt = ed1 - e21;                                                   \
        float k1 = e20 * dlt;                                                    \
        float k0 = fmaf(beta0, dlt, ec1);                                        \
        float a = A0, c = e20 * A0, d = A1;                                      \
        float bu = sP, bv = eb0;                                                 \
        MSTAGE(0x111, 0xF) MSTAGE(0x112, 0xF) MSTAGE(0x114, 0xF)                 \
        MSTAGE(0x118, 0xF) MSTAGE(0x142, 0xA) MSTAGE(0x143, 0xC)                 \
        float u = bu, v = bv;                                                    \
        float s31 = fmaf(v, e21, fmaf(u, k1, k0));                               \
        if (s < DP_BLOCKS - 1) {                                                 \
            if (lane == 63) {                                                    \
                Pair t0 = pcomb(cin0, Pair{G0, u});                              \
                Pair t1 = pcomb(cin1, Pair{G1, v});                              \
                unsigned long long p0 =                                          \
                    ((unsigned long long)__float_as_uint(t0.s) << 32)            \
                    | (unsigned long long)__float_as_uint(t0.m);                 \
                unsigned long long p1 =                                          \
                    ((unsigned long long)__float_as_uint(t1.s) << 32)            \
                    | (unsigned long long)__float_as_uint(t1.m);                 \
                __hip_atomic_store(pub + row, p0, __ATOMIC_RELAXED,              \
                                   __HIP_MEMORY_SCOPE_AGENT);                    \
                __hip_atomic_store(pub + row + 1, p1, __ATOMIC_RELAXED,          \
                                   __HIP_MEMORY_SCOPE_AGENT);                    \
            }                                                                    \
        } else {                                                                 \
            Pair t0 = pcomb(cin0, Pair{G0, u});                                  \
            Pair h0 = pcomb(t0, Pair{mH + lwe0, sH});                            \
            mH = h0.m; sH = h0.s; renorm(mH, sH);                                \
            Pair t1 = pcomb(cin1, Pair{G1, v});                                  \
            Pair h1 = pcomb(t1, Pair{mH + lwe1, sH});                            \
            mH = h1.m; sH = h1.s; renorm(mH, sH);                                \
        }                                                                        \
        float mN = m31;                                                          \
        if (RN) {                                                                \
            mN = m31 + (float)__builtin_amdgcn_frexp_expf(s31);                  \
            s31 = __builtin_amdgcn_frexp_mantf(s31);                             \
        }                                                                        \
        mP = mN; sP = s31;                                                       \
    }

// Wait for the 4-row group we are about to consume.  While spinning, refresh
// ALL stale flags of the band (overlaps later groups' propagation latency with
// this wait); after exiting, issue one speculative refresh for the next group
// so its cross-XCD visibility latency hides under this group's compute.
#define WAIT_GROUP(g)                                                            \
    if (s > 0) {                                                                 \
        for (;;) {                                                               \
            unsigned long long miss =                                            \
                __ballot(((lane >> 2) == (g)) && pk == 0ull);                    \
            if (miss == 0ull) break;                                             \
            if (pk == 0ull && (lane >> 2) >= (g))                                \
                pk = __hip_atomic_load(sub + base + lane, __ATOMIC_RELAXED,      \
                                       __HIP_MEMORY_SCOPE_AGENT);               \
        }                                                                        \
        if (pk == 0ull && (lane >> 2) > (g))                                     \
            pk = __hip_atomic_load(sub + base + lane, __ATOMIC_RELAXED,          \
                                   __HIP_MEMORY_SCOPE_AGENT);                   \
        pkLo = (int)(unsigned)(pk & 0xFFFFFFFFull);                              \
        pkHi = (int)(unsigned)(pk >> 32);                                        \
    }

__global__ __launch_bounds__(64) void dp_kernel(const float* __restrict__ LG2T,
                                                const float* __restrict__ Rs,
                                                unsigned long long* __restrict__ carry,
                                                float* __restrict__ out) {
    const int s = ((blockIdx.x & 7) << 2) | (blockIdx.x >> 3);  // XCD-aware stripe id
    const int lane = threadIdx.x;
    const float* lcol = LG2T + (size_t)(s * DP_COLS + lane) * M_ROWS;
    unsigned long long* pub = carry + (size_t)s * M_ROWS;
    const unsigned long long* sub = carry + (size_t)(s - 1) * M_ROWS;

    float mP = 0.f, sP = 1.f;      // virtual row -1: P = log2(1)
    float mH = 0.f, sH = 1.f;      // stripe 31, lane 63 only

    float4 lq0 = *(const float4*)(lcol + 0);
    float4 lq1 = *(const float4*)(lcol + 4);
    float4 lq2 = *(const float4*)(lcol + 8);
    float4 lq3 = *(const float4*)(lcol + 12);
    float4 rv0 = *(const float4*)(Rs + 0);
    float4 rv1 = *(const float4*)(Rs + 4);
    float4 rv2 = *(const float4*)(Rs + 8);
    float4 rv3 = *(const float4*)(Rs + 12);

    // speculative carry prefetch for band 0
    unsigned long long pk = 1ull;
    if (s > 0 && lane < BAND)
        pk = __hip_atomic_load(sub + lane, __ATOMIC_RELAXED, __HIP_MEMORY_SCOPE_AGENT);

    for (int base = 0; base < M_ROWS; base += BAND) {
        // prefetch next band's weights (independent; completes during the 16 rows)
        float4 nl0{}, nl1{}, nl2{}, nl3{}, nv0{}, nv1{}, nv2{}, nv3{};
        if (base + BAND < M_ROWS) {
            nl0 = *(const float4*)(lcol + base + BAND);
            nl1 = *(const float4*)(lcol + base + BAND + 4);
            nl2 = *(const float4*)(lcol + base + BAND + 8);
            nl3 = *(const float4*)(lcol + base + BAND + 12);
            nv0 = *(const float4*)(Rs + base + BAND);
            nv1 = *(const float4*)(Rs + base + BAND + 4);
            nv2 = *(const float4*)(Rs + base + BAND + 8);
            nv3 = *(const float4*)(Rs + base + BAND + 12);
        }
        int pkLo = 0, pkHi = 0;

        WAIT_GROUP(0)
        DP_PAIR(0,  lq0.x, rv0.x, lq0.y, rv0.y, 0)
        DP_PAIR(2,  lq0.z, rv0.z, lq0.w, rv0.w, 1)
        WAIT_GROUP(1)
        DP_PAIR(4,  lq1.x, rv1.x, lq1.y, rv1.y, 0)
        DP_PAIR(6,  lq1.z, rv1.z, lq1.w, rv1.w, 1)
        WAIT_GROUP(2)
        DP_PAIR(8,  lq2.x, rv2.x, lq2.y, rv2.y, 0)
        DP_PAIR(10, lq2.z, rv2.z, lq2.w, rv2.w, 1)
        WAIT_GROUP(3)
        // speculative carry load for the NEXT band (in flight during rows 12-15
        // and the next band's weight prefetch)
        {
            unsigned long long nk = 1ull;
            if (s > 0 && lane < BAND && base + BAND < M_ROWS)
                nk = __hip_atomic_load(sub + base + BAND + lane,
                                       __ATOMIC_RELAXED, __HIP_MEMORY_SCOPE_AGENT);
            DP_PAIR(12, lq3.x, rv3.x, lq3.y, rv3.y, 0)
            DP_PAIR(14, lq3.z, rv3.z, lq3.w, rv3.w, 1)
            pk = nk;
        }

        lq0 = nl0; lq1 = nl1; lq2 = nl2; lq3 = nl3;
        rv0 = nv0; rv1 = nv1; rv2 = nv2; rv3 = nv3;
    }
    if (s == DP_BLOCKS - 1 && lane == 63)
        out[0] = -GAMMA * LN2 * (mH + flog2(sH));
}

extern "C" void kernel_launch(void* const* d_in, const int* in_sizes, int n_in,
                              void* d_out, int out_size, void* d_ws, size_t ws_size,
                              hipStream_t stream) {
    (void)in_sizes; (void)n_in; (void)out_size; (void)ws_size;
    const float* a = (const float*)d_in[0];
    const float* b = (const float*)d_in[1];
    float* out = (float*)d_out;
    char* ws = (char*)d_ws;
    float* Q        = (float*)(ws);                                    // 16 MB
    float* LG2T     = (float*)(ws + (size_t)16 * 1024 * 1024);         // 16 MB
    float* Ahat     = (float*)(ws + (size_t)32 * 1024 * 1024);         // 4 MB
    float* Bhat     = (float*)(ws + (size_t)36 * 1024 * 1024);         // 4 MB
    float* rowscale = (float*)(ws + (size_t)40 * 1024 * 1024);         // 8 KB
    int* permA      = (int*)(ws + (size_t)40 * 1024 * 1024 + 8192);    // 8 KB
    int* permB      = (int*)(ws + (size_t)40 * 1024 * 1024 + 16384);   // 8 KB
    unsigned long long* carry = (unsigned long long*)(ws + (size_t)41 * 1024 * 1024); // 512 KB

    hipMemsetAsync(carry, 0, (size_t)DP_BLOCKS * M_ROWS * sizeof(unsigned long long), stream);
    argsort_kernel<<<dim3(8, 2), 256, 0, stream>>>(a, b, permA, permB);
    norm_kernel<<<dim3(2048, 2), 128, 0, stream>>>(a, b, permA, permB, Ahat, Bhat);
    gemm_kernel<<<dim3(32, 32), 256, 0, stream>>>(Ahat, Bhat, Q);
    rowstat_kernel<<<2048, 256, 0, stream>>>(Q, rowscale);
    lgt_kernel<<<dim3(32, 32), 256, 0, stream>>>(Q, rowscale, LG2T);
    dp_kernel<<<DP_BLOCKS, DP_COLS, 0, stream>>>(LG2T, rowscale, carry, out);
}

// Round 3
// 682.144 us; speedup vs baseline: 1.3987x; 1.3180x over previous
//
#include <hip/hip_runtime.h>
#include <math.h>

#define M_ROWS 2048
#define N_COLS 2048
#define DIMS 512
#define IN_STRIDE 513
#define DP_BLOCKS 32
#define DP_COLS 64
#define BAND 16

constexpr float GAMMA = 0.001f;
constexpr float LOG2E = 1.44269504088896f;
constexpr float LN2   = 0.69314718055995f;

__device__ __forceinline__ float fexp2(float x) { return __builtin_amdgcn_exp2f(x); }
__device__ __forceinline__ float flog2(float x) { return __builtin_amdgcn_logf(x); }

// ---------------- argsort by timestamp (last column), stable ----------------
__global__ void argsort_kernel(const float* __restrict__ a, const float* __restrict__ b,
                               int* __restrict__ permA, int* __restrict__ permB) {
    const float* src = blockIdx.y ? b : a;
    int* perm = blockIdx.y ? permB : permA;
    __shared__ float keys[M_ROWS];
    for (int j = threadIdx.x; j < M_ROWS; j += blockDim.x)
        keys[j] = src[(size_t)j * IN_STRIDE + DIMS];
    __syncthreads();
    int i = blockIdx.x * blockDim.x + threadIdx.x;
    float ki = keys[i];
    int rank = 0;
    for (int j = 0; j < M_ROWS; ++j) {
        float kj = keys[j];
        rank += (kj < ki) || (kj == ki && j < i);
    }
    perm[rank] = i;
}

// ---------------- gather sorted rows + L2-normalize (drop time col) ----------------
__global__ __launch_bounds__(128) void norm_kernel(const float* __restrict__ a, const float* __restrict__ b,
                                                   const int* __restrict__ permA, const int* __restrict__ permB,
                                                   float* __restrict__ Ahat, float* __restrict__ Bhat) {
    const float* src = blockIdx.y ? b : a;
    const int* perm = blockIdx.y ? permB : permA;
    float* dst = blockIdx.y ? Bhat : Ahat;
    int r = blockIdx.x;
    int row = perm[r];
    const float* p = src + (size_t)row * IN_STRIDE;
    int tid = threadIdx.x;
    float v0 = p[tid], v1 = p[tid + 128], v2 = p[tid + 256], v3 = p[tid + 384];
    float ss = v0 * v0 + v1 * v1 + v2 * v2 + v3 * v3;
    #pragma unroll
    for (int off = 32; off > 0; off >>= 1) ss += __shfl_down(ss, off);
    __shared__ float red[2];
    if ((tid & 63) == 0) red[tid >> 6] = ss;
    __syncthreads();
    float inv = 1.0f / sqrtf(red[0] + red[1] + 1e-10f);
    float* q = dst + (size_t)r * DIMS;
    q[tid] = v0 * inv; q[tid + 128] = v1 * inv; q[tid + 256] = v2 * inv; q[tid + 384] = v3 * inv;
}

// ---------------- GEMM: Q[i][n] = exp(-1 - dot(Ahat[i], Bhat[n])) ----------------
__global__ __launch_bounds__(256) void gemm_kernel(const float* __restrict__ A, const float* __restrict__ B,
                                                   float* __restrict__ Q) {
    __shared__ float As[16][68];
    __shared__ float Bs[16][68];
    int tid = threadIdx.x;
    int tx = tid & 15, ty = tid >> 4;
    int row0 = blockIdx.y * 64;
    int col0 = blockIdx.x * 64;
    int lrow = tid >> 2;
    int lk = (tid & 3) * 4;
    const float* ap = A + (size_t)(row0 + lrow) * DIMS + lk;
    const float* bp = B + (size_t)(col0 + lrow) * DIMS + lk;
    float acc[4][4] = {};
    for (int k0 = 0; k0 < DIMS; k0 += 16) {
        float4 av = *(const float4*)ap; ap += 16;
        float4 bv = *(const float4*)bp; bp += 16;
        __syncthreads();
        As[lk + 0][lrow] = av.x; As[lk + 1][lrow] = av.y; As[lk + 2][lrow] = av.z; As[lk + 3][lrow] = av.w;
        Bs[lk + 0][lrow] = bv.x; Bs[lk + 1][lrow] = bv.y; Bs[lk + 2][lrow] = bv.z; Bs[lk + 3][lrow] = bv.w;
        __syncthreads();
        #pragma unroll
        for (int k = 0; k < 16; ++k) {
            float4 a4 = *(const float4*)&As[k][ty * 4];
            float4 b4 = *(const float4*)&Bs[k][tx * 4];
            float aa[4] = {a4.x, a4.y, a4.z, a4.w};
            float bb[4] = {b4.x, b4.y, b4.z, b4.w};
            #pragma unroll
            for (int u = 0; u < 4; ++u)
                #pragma unroll
                for (int v = 0; v < 4; ++v)
                    acc[u][v] += aa[u] * bb[v];
        }
    }
    #pragma unroll
    for (int u = 0; u < 4; ++u) {
        float4 o;
        o.x = __expf(-1.0f - acc[u][0]);
        o.y = __expf(-1.0f - acc[u][1]);
        o.z = __expf(-1.0f - acc[u][2]);
        o.w = __expf(-1.0f - acc[u][3]);
        *(float4*)&Q[(size_t)(row0 + ty * 4 + u) * N_COLS + col0 + tx * 4] = o;
    }
}

// ------- per-row softmax denom -> rs = log2e/(gamma*denom); also Ew = 2^-rs -------
__global__ __launch_bounds__(256) void rowstat_kernel(const float* __restrict__ Q,
                                                      float* __restrict__ rowscale,
                                                      float* __restrict__ ews) {
    int i = blockIdx.x;
    const float* q = Q + (size_t)i * N_COLS;
    int tid = threadIdx.x;
    float4 x = *(const float4*)(q + tid * 4);
    float4 y = *(const float4*)(q + 1024 + tid * 4);
    float s = x.x + x.y + x.z + x.w + y.x + y.y + y.z + y.w;
    #pragma unroll
    for (int off = 32; off > 0; off >>= 1) s += __shfl_down(s, off);
    __shared__ float red[4];
    if ((tid & 63) == 0) red[tid >> 6] = s;
    __syncthreads();
    if (tid == 0) {
        float denom = 2049.0f + red[0] + red[1] + red[2] + red[3];
        float rs = (LOG2E / GAMMA) / denom;
        rowscale[i] = rs;
        ews[i] = fexp2(-rs);
    }
}

// ---- ELT[col][row] = 2^-rs + 2^(-rs*Q[row][col])  (LINEAR weight), transposed ----
__global__ __launch_bounds__(256) void lgt_kernel(const float* __restrict__ Q,
                                                  const float* __restrict__ rowscale,
                                                  float* __restrict__ ELT) {
    __shared__ float tile[64][65];
    const int row0 = blockIdx.y * 64;
    const int col0 = blockIdx.x * 64;
    const int t = threadIdx.x;
    const int c4 = (t & 15) * 4;
    const int r  = t >> 4;           // 0..15
    #pragma unroll
    for (int rr = 0; rr < 64; rr += 16) {
        int row = row0 + rr + r;
        float rs = rowscale[row];
        float4 v = *(const float4*)(Q + (size_t)row * N_COLS + col0 + c4);
        float e = fexp2(-rs);
        tile[c4 + 0][rr + r] = e + fexp2(-rs * v.x);
        tile[c4 + 1][rr + r] = e + fexp2(-rs * v.y);
        tile[c4 + 2][rr + r] = e + fexp2(-rs * v.z);
        tile[c4 + 3][rr + r] = e + fexp2(-rs * v.w);
    }
    __syncthreads();
    #pragma unroll
    for (int cc = 0; cc < 64; cc += 16) {
        int col = cc + r;
        float4 o;
        o.x = tile[col][c4 + 0];
        o.y = tile[col][c4 + 1];
        o.z = tile[col][c4 + 2];
        o.w = tile[col][c4 + 3];
        *(float4*)(ELT + (size_t)(col0 + col) * M_ROWS + row0 + c4) = o;
    }
}

template<int CTRL, int ROWM>
__device__ __forceinline__ float fdpp(float oldv, float src) {
    return __int_as_float(__builtin_amdgcn_update_dpp(
        __float_as_int(oldv), __float_as_int(src), CTRL, ROWM, 0xF, false));
}

// ---------------- linear-space row body ----------------
// State: wave-uniform exponent Rm (renormed every 4 rows) + per-lane mantissa
// w[n] = 2^(V[n]-Rm), V = the column's prefix-softmin DP value (log2 domain).
// Row update (exact re-association of the verified recurrence):
//   w_new[n] = ci + sum_{k<n} w[k]*EL[k] + w[n]*Ew
// where EL = 2^(LG2T) (stored linear in ELT), Ew = 2^(-rs) (precomputed array),
// ci = carry-in scaled by 2^(cm - Rm) (cm = producer's Rm, constant per 4-row
// group -> cf hoisted to WAIT_GROUP).  Plain +-scan (6 dpp-adds), no per-lane
// exp2, no max bookkeeping.  Publish: {lo=Rm, hi=ci+incl[63]} (hi>0 => pk!=0).
// Stripe-31 head H_i = LSE(tot_i, H_{i-1}+lwe) becomes h = h*Ew + all (1 fma);
// only lane 63's h is meaningful (its 'all' is the true row total).
#define DP_ROW(U, ELV, EWV)                                                      \
    {                                                                            \
        float ci = 0.f;                                                          \
        if (s > 0)                                                               \
            ci = __int_as_float(__builtin_amdgcn_readlane(pkHi, (U))) * cf;      \
        float y = w * (ELV);                                                     \
        float t = y;                                                             \
        t += fdpp<0x111, 0xF>(0.f, t);                                           \
        t += fdpp<0x112, 0xF>(0.f, t);                                           \
        t += fdpp<0x114, 0xF>(0.f, t);                                           \
        t += fdpp<0x118, 0xF>(0.f, t);                                           \
        t += fdpp<0x142, 0xA>(0.f, t);                                           \
        t += fdpp<0x143, 0xC>(0.f, t);                                           \
        float all = ci + t;                                                      \
        float wn = fmaf(w, (EWV), ci) + (t - y);                                 \
        if (s < DP_BLOCKS - 1) {                                                 \
            if (lane == 63) {                                                    \
                unsigned long long po =                                          \
                    ((unsigned long long)__float_as_uint(all) << 32)             \
                    | (unsigned long long)__float_as_uint(Rm);                   \
                __hip_atomic_store(pub + base + (U), po, __ATOMIC_RELAXED,       \
                                   __HIP_MEMORY_SCOPE_AGENT);                    \
            }                                                                    \
        } else {                                                                 \
            h = fmaf(h, (EWV), all);                                             \
        }                                                                        \
        w = wn;                                                                  \
    }

// Renorm the shared exponent from lane 48's mantissa (columns are tightly
// coupled through the prefix-softmin, so intra-wave spread is small).  Runs at
// group boundaries only, so Rm is constant within each published 4-row group.
#define RENORM4                                                                  \
    {                                                                            \
        int e48 = __builtin_amdgcn_readlane(__builtin_amdgcn_frexp_expf(w), 48); \
        float f = __int_as_float((127 - e48) << 23);                             \
        w *= f; h *= f;                                                          \
        Rm += (float)e48;                                                        \
    }

// Wait for the 4-row group we are about to consume; refresh stale flags of this
// and later groups while spinning.  cf = 2^(producer_Rm - Rm) for the group.
#define WAIT_GROUP(g)                                                            \
    if (s > 0) {                                                                 \
        for (;;) {                                                               \
            unsigned long long miss =                                            \
                __ballot(((lane >> 2) == (g)) && pk == 0ull);                    \
            if (miss == 0ull) break;                                             \
            if (pk == 0ull && (lane >> 2) >= (g))                                \
                pk = __hip_atomic_load(sub + base + lane, __ATOMIC_RELAXED,      \
                                       __HIP_MEMORY_SCOPE_AGENT);               \
        }                                                                        \
        pkLo = (int)(unsigned)(pk & 0xFFFFFFFFull);                              \
        pkHi = (int)(unsigned)(pk >> 32);                                        \
        cf = fexp2(__int_as_float(__builtin_amdgcn_readlane(pkLo, 4 * (g))) - Rm); \
    }

__global__ __launch_bounds__(64) void dp_kernel(const float* __restrict__ ELT,
                                                const float* __restrict__ Ews,
                                                unsigned long long* __restrict__ carry,
                                                float* __restrict__ out) {
    const int s = ((blockIdx.x & 7) << 2) | (blockIdx.x >> 3);  // XCD-aware stripe id
    const int lane = threadIdx.x;
    const float* lcol = ELT + (size_t)(s * DP_COLS + lane) * M_ROWS;
    unsigned long long* pub = carry + (size_t)s * M_ROWS;
    const unsigned long long* sub = carry + (size_t)(s - 1) * M_ROWS;

    float w = 1.f;                 // virtual row -1: V = 0 for every column
    float Rm = 0.f;                // shared exponent
    float h = 1.f;                 // head accumulator (stripe 31, lane 63)
    float cf = 0.f;

    float4 lq0 = *(const float4*)(lcol + 0);
    float4 lq1 = *(const float4*)(lcol + 4);
    float4 lq2 = *(const float4*)(lcol + 8);
    float4 lq3 = *(const float4*)(lcol + 12);
    float4 ev0 = *(const float4*)(Ews + 0);
    float4 ev1 = *(const float4*)(Ews + 4);
    float4 ev2 = *(const float4*)(Ews + 8);
    float4 ev3 = *(const float4*)(Ews + 12);

    // speculative carry prefetch for band 0
    unsigned long long pk = 1ull;
    if (s > 0 && lane < BAND)
        pk = __hip_atomic_load(sub + lane, __ATOMIC_RELAXED, __HIP_MEMORY_SCOPE_AGENT);

    for (int base = 0; base < M_ROWS; base += BAND) {
        // prefetch next band's weights (independent; completes during the 16 rows)
        float4 nl0{}, nl1{}, nl2{}, nl3{}, nv0{}, nv1{}, nv2{}, nv3{};
        if (base + BAND < M_ROWS) {
            nl0 = *(const float4*)(lcol + base + BAND);
            nl1 = *(const float4*)(lcol + base + BAND + 4);
            nl2 = *(const float4*)(lcol + base + BAND + 8);
            nl3 = *(const float4*)(lcol + base + BAND + 12);
            nv0 = *(const float4*)(Ews + base + BAND);
            nv1 = *(const float4*)(Ews + base + BAND + 4);
            nv2 = *(const float4*)(Ews + base + BAND + 8);
            nv3 = *(const float4*)(Ews + base + BAND + 12);
        }
        int pkLo = 0, pkHi = 0;

        WAIT_GROUP(0)
        DP_ROW(0,  lq0.x, ev0.x)
        DP_ROW(1,  lq0.y, ev0.y)
        DP_ROW(2,  lq0.z, ev0.z)
        DP_ROW(3,  lq0.w, ev0.w)
        RENORM4
        WAIT_GROUP(1)
        DP_ROW(4,  lq1.x, ev1.x)
        DP_ROW(5,  lq1.y, ev1.y)
        DP_ROW(6,  lq1.z, ev1.z)
        DP_ROW(7,  lq1.w, ev1.w)
        RENORM4
        WAIT_GROUP(2)
        DP_ROW(8,  lq2.x, ev2.x)
        DP_ROW(9,  lq2.y, ev2.y)
        DP_ROW(10, lq2.z, ev2.z)
        DP_ROW(11, lq2.w, ev2.w)
        RENORM4
        WAIT_GROUP(3)
        // speculative carry load for the NEXT band (in flight during rows 12-15
        // and the next band's weight prefetch)
        {
            unsigned long long nk = 1ull;
            if (s > 0 && lane < BAND && base + BAND < M_ROWS)
                nk = __hip_atomic_load(sub + base + BAND + lane,
                                       __ATOMIC_RELAXED, __HIP_MEMORY_SCOPE_AGENT);
            DP_ROW(12, lq3.x, ev3.x)
            DP_ROW(13, lq3.y, ev3.y)
            DP_ROW(14, lq3.z, ev3.z)
            DP_ROW(15, lq3.w, ev3.w)
            RENORM4
            pk = nk;
        }

        lq0 = nl0; lq1 = nl1; lq2 = nl2; lq3 = nl3;
        ev0 = nv0; ev1 = nv1; ev2 = nv2; ev3 = nv3;
    }
    if (s == DP_BLOCKS - 1 && lane == 63)
        out[0] = -GAMMA * LN2 * (Rm + flog2(h));
}

extern "C" void kernel_launch(void* const* d_in, const int* in_sizes, int n_in,
                              void* d_out, int out_size, void* d_ws, size_t ws_size,
                              hipStream_t stream) {
    (void)in_sizes; (void)n_in; (void)out_size; (void)ws_size;
    const float* a = (const float*)d_in[0];
    const float* b = (const float*)d_in[1];
    float* out = (float*)d_out;
    char* ws = (char*)d_ws;
    float* Q        = (float*)(ws);                                    // 16 MB
    float* ELT      = (float*)(ws + (size_t)16 * 1024 * 1024);         // 16 MB
    float* Ahat     = (float*)(ws + (size_t)32 * 1024 * 1024);         // 4 MB
    float* Bhat     = (float*)(ws + (size_t)36 * 1024 * 1024);         // 4 MB
    float* rowscale = (float*)(ws + (size_t)40 * 1024 * 1024);         // 8 KB
    int* permA      = (int*)(ws + (size_t)40 * 1024 * 1024 + 8192);    // 8 KB
    int* permB      = (int*)(ws + (size_t)40 * 1024 * 1024 + 16384);   // 8 KB
    float* ews      = (float*)(ws + (size_t)40 * 1024 * 1024 + 24576); // 8 KB
    unsigned long long* carry = (unsigned long long*)(ws + (size_t)41 * 1024 * 1024); // 512 KB

    hipMemsetAsync(carry, 0, (size_t)DP_BLOCKS * M_ROWS * sizeof(unsigned long long), stream);
    argsort_kernel<<<dim3(8, 2), 256, 0, stream>>>(a, b, permA, permB);
    norm_kernel<<<dim3(2048, 2), 128, 0, stream>>>(a, b, permA, permB, Ahat, Bhat);
    gemm_kernel<<<dim3(32, 32), 256, 0, stream>>>(Ahat, Bhat, Q);
    rowstat_kernel<<<2048, 256, 0, stream>>>(Q, rowscale, ews);
    lgt_kernel<<<dim3(32, 32), 256, 0, stream>>>(Q, rowscale, ELT);
    dp_kernel<<<DP_BLOCKS, DP_COLS, 0, stream>>>(ELT, ews, carry, out);
}